// Round 3
// baseline (279.617 us; speedup 1.0000x reference)
//
#include <hip/hip_runtime.h>

#define Bn 256
#define Ln 512
#define Tn 32
#define START_S 30
#define STOP_S 31

typedef short bf16x8 __attribute__((ext_vector_type(8)));
typedef float f32x16 __attribute__((ext_vector_type(16)));

union FragU { int i[4]; bf16x8 v; };

__device__ __forceinline__ int cvt_pk(float lo, float hi) {
    int r;
    asm volatile("v_cvt_pk_bf16_f32 %0, %1, %2" : "=v"(r) : "v"(lo), "v"(hi));
    return r;
}

__device__ __forceinline__ bf16x8 pack8(const float* x) {
    FragU u;
    u.i[0] = cvt_pk(x[0], x[1]);
    u.i[1] = cvt_pk(x[2], x[3]);
    u.i[2] = cvt_pk(x[4], x[5]);
    u.i[3] = cvt_pk(x[6], x[7]);
    return u.v;
}

__device__ __forceinline__ float bf2f(short v) {
    return __uint_as_float(((unsigned)(unsigned short)v) << 16);
}

// blocks 0..7: batched forward recursion (32 batch rows per block, MFMA).
// blocks 8..2055: gold score, 1 (b,l) pair per thread.
__global__ __launch_bounds__(64) void crf_all_kernel(
    const float* __restrict__ feats,
    const unsigned char* __restrict__ maskb,
    const int* __restrict__ tags,
    const float* __restrict__ trans,
    float* __restrict__ out)
{
    const int mst = (maskb[1] != 0) ? 1 : 4;   // bool(1B) vs int32 mask storage

    if (blockIdx.x >= 8) {
        // ---------------- gold score ----------------
        int t = (blockIdx.x - 8) * 64 + threadIdx.x;   // 0..131071
        int b = t >> 9, l = t & 511;
        const unsigned char* mrow = maskb + (size_t)b * Ln * mst;
        float g = 0.f;
        if (mrow[(size_t)l * mst] != 0) {
            int cur  = tags[b * Ln + l];
            int prev = (l == 0) ? START_S : tags[b * Ln + l - 1];
            g = feats[((size_t)b * Ln + l) * Tn + cur] + trans[prev * Tn + cur];
            bool last = (l == Ln - 1) || (mrow[(size_t)(l + 1) * mst] == 0);
            if (last) g += trans[cur * Tn + STOP_S];   // end energy
        }
        g += __shfl_xor(g, 1);  g += __shfl_xor(g, 2);  g += __shfl_xor(g, 4);
        g += __shfl_xor(g, 8);  g += __shfl_xor(g, 16); g += __shfl_xor(g, 32);
        if (threadIdx.x == 0) atomicAdd(out, -g);
        return;
    }

    // ---------------- batched forward (MFMA) ----------------
    const int lane = threadIdx.x;
    const int c = lane & 31;          // batch column within tile
    const int h = lane >> 5;          // half-wave (k/j sub-range selector)
    const int b = blockIdx.x * 32 + c;
    const float* frow = feats + (size_t)b * (Ln * Tn);

    // per-row length via binary search on the monotone mask row (len >= 256)
    const unsigned char* mrow = maskb + (size_t)b * Ln * mst;
    int lo = 255, hi = 512;
    #pragma unroll
    for (int it = 0; it < 9; ++it) {
        int mid = (lo + hi) >> 1;
        bool mv = mrow[(size_t)mid * mst] != 0;
        lo = mv ? mid : lo;
        hi = mv ? hi : mid;
    }
    const int len = hi;

    // A-operands: Wt[m=c][k] = exp(trans[k][c]); A1: k=8h+e, A2: k=16+8h+e
    float xa[8];
    #pragma unroll
    for (int e = 0; e < 8; ++e) xa[e] = __expf(trans[(8 * h + e) * Tn + c]);
    const bf16x8 A1 = pack8(xa);
    #pragma unroll
    for (int e = 0; e < 8; ++e) xa[e] = __expf(trans[(16 + 8 * h + e) * Tn + c]);
    const bf16x8 A2 = pack8(xa);

    // initial P (l=0): P0[j][b] = exp(feats[b][0][j] + trans[START][j])
    FragU b1, b2;
    {
        float xb[8];
        #pragma unroll
        for (int e = 0; e < 8; ++e) {
            int j = 8 * h + e;
            xb[e] = __expf(frow[j] + trans[START_S * Tn + j]);
        }
        b1.v = pack8(xb);
        #pragma unroll
        for (int e = 0; e < 8; ++e) {
            int j = 16 + 8 * h + e;
            xb[e] = __expf(frow[j] + trans[START_S * Tn + j]);
        }
        b2.v = pack8(xb);
    }

    const f32x16 fzero = {0.f};
    float M = 0.f;

    // F prefetch: lane (h,c) needs rows j = 8g+4h .. +3 per reg-group g
    const float4* f4 = (const float4*)frow;
    float4 fA[4];
    #pragma unroll
    for (int g = 0; g < 4; ++g) fA[g] = f4[1 * 8 + 2 * g + h];

    for (int l = 1; l < Ln; ++l) {
        float E[16];
        #pragma unroll
        for (int g = 0; g < 4; ++g) {
            E[4 * g + 0] = __expf(fA[g].x);
            E[4 * g + 1] = __expf(fA[g].y);
            E[4 * g + 2] = __expf(fA[g].z);
            E[4 * g + 3] = __expf(fA[g].w);
        }
        if (l < Ln - 1) {
            #pragma unroll
            for (int g = 0; g < 4; ++g) fA[g] = f4[(l + 1) * 8 + 2 * g + h];
        }

        f32x16 acc = __builtin_amdgcn_mfma_f32_32x32x16_bf16(A1, b1.v, fzero, 0, 0, 0);
        acc = __builtin_amdgcn_mfma_f32_32x32x16_bf16(A2, b2.v, acc, 0, 0, 0);

        const bool act = (l < len);
        float V[16];
        if ((l & 7) == 0) {                 // rescale (uniform branch)
            float c0 = acc[1];              // row j=1 for h=0 lanes
            float cs = __shfl_xor(c0, 32);
            float cb = h ? cs : c0;         // same normalizer in both halves
            cb = act ? cb : 1.0f;           // frozen columns: no rescale
            float inv = 1.0f / cb;
            M += __logf(cb);
            #pragma unroll
            for (int r = 0; r < 16; ++r) V[r] = acc[r] * inv * E[r];
        } else {
            #pragma unroll
            for (int r = 0; r < 16; ++r) V[r] = acc[r] * E[r];
        }

        // fp32 -> bf16 pairs; q[t] holds rows j = 8*(t>>1) + 4h + {2*(t&1), +1}
        int q0 = cvt_pk(V[0],  V[1]),  q1 = cvt_pk(V[2],  V[3]);
        int q2 = cvt_pk(V[4],  V[5]),  q3 = cvt_pk(V[6],  V[7]);
        int q4 = cvt_pk(V[8],  V[9]),  q5 = cvt_pk(V[10], V[11]);
        int q6 = cvt_pk(V[12], V[13]), q7 = cvt_pk(V[14], V[15]);

        int s0 = __shfl_xor(q0, 32), s1 = __shfl_xor(q1, 32);
        int s2 = __shfl_xor(q2, 32), s3 = __shfl_xor(q3, 32);
        int s4 = __shfl_xor(q4, 32), s5 = __shfl_xor(q5, 32);
        int s6 = __shfl_xor(q6, 32), s7 = __shfl_xor(q7, 32);

        int n10 = h ? s2 : q0, n11 = h ? s3 : q1;
        int n12 = h ? q2 : s0, n13 = h ? q3 : s1;
        int n20 = h ? s6 : q4, n21 = h ? s7 : q5;
        int n22 = h ? q6 : s4, n23 = h ? q7 : s5;

        b1.i[0] = act ? n10 : b1.i[0];  b1.i[1] = act ? n11 : b1.i[1];
        b1.i[2] = act ? n12 : b1.i[2];  b1.i[3] = act ? n13 : b1.i[3];
        b2.i[0] = act ? n20 : b2.i[0];  b2.i[1] = act ? n21 : b2.i[1];
        b2.i[2] = act ? n22 : b2.i[2];  b2.i[3] = act ? n23 : b2.i[3];
    }

    // final LSE into STOP: s_b = sum_j P[j][b] * exp(trans[j][STOP])
    float s = 0.f;
    #pragma unroll
    for (int e = 0; e < 8; ++e) {
        float w1 = __expf(trans[(8 * h + e) * Tn + STOP_S]);
        float w2 = __expf(trans[(16 + 8 * h + e) * Tn + STOP_S]);
        s += bf2f(b1.v[e]) * w1 + bf2f(b2.v[e]) * w2;
    }
    s += __shfl_xor(s, 32);                 // combine the two halves
    float fwd = M + __logf(s);

    float tot = fwd;                        // sum over the 32 columns (each half has all 32)
    tot += __shfl_xor(tot, 1);  tot += __shfl_xor(tot, 2);
    tot += __shfl_xor(tot, 4);  tot += __shfl_xor(tot, 8);
    tot += __shfl_xor(tot, 16);
    if (lane == 0) atomicAdd(out, tot);
}

extern "C" void kernel_launch(void* const* d_in, const int* in_sizes, int n_in,
                              void* d_out, int out_size, void* d_ws, size_t ws_size,
                              hipStream_t stream) {
    const float* feats = (const float*)d_in[0];
    const unsigned char* maskb = (const unsigned char*)d_in[1];
    const int* tags = (const int*)d_in[2];
    const float* trans = (const float*)d_in[3];
    float* out = (float*)d_out;

    hipMemsetAsync(out, 0, sizeof(float), stream);
    crf_all_kernel<<<8 + 2048, 64, 0, stream>>>(feats, maskb, tags, trans, out);
}

// Round 4
// 87.016 us; speedup vs baseline: 3.2134x; 3.2134x over previous
//
#include <hip/hip_runtime.h>

#define Bn 256
#define Ln 512
#define Tn 32
#define START_S 30
#define STOP_S 31
#define LN64 4.158883083359672f   // ln(64)

typedef short bf16x8 __attribute__((ext_vector_type(8)));
typedef float f32x16 __attribute__((ext_vector_type(16)));
union FragU { int i[4]; unsigned u[4]; bf16x8 v; };

__device__ __forceinline__ int cvt_pk(float lo, float hi) {
    int r;
    asm volatile("v_cvt_pk_bf16_f32 %0, %1, %2" : "=v"(r) : "v"(lo), "v"(hi));
    return r;
}
__device__ __forceinline__ float rdlane(float x, int l) {
    return __int_as_float(__builtin_amdgcn_readlane(__float_as_int(x), l));
}
__device__ __forceinline__ float bf2f(unsigned short v) {
    return __uint_as_float(((unsigned)v) << 16);
}

// One block per batch row b. 16 waves: wave w owns L-chunk [1+32w, 33+32w).
// Phase 1: gold score (waves 0-7), p0 (wave 8), chunk products (all waves).
// Phase 2: 4-level MFMA tree combine. Phase 3: matvec + LSE + atomicAdd.
__global__ __launch_bounds__(1024, 1) void crf_scan_kernel(
    const float* __restrict__ feats,
    const unsigned char* __restrict__ maskb,
    const int* __restrict__ tags,
    const float* __restrict__ trans,
    float* __restrict__ out)
{
    __shared__ unsigned short QL[16][32][34];  // [chunk][col c][row] bf16, padded
    __shared__ float logsL[16];
    __shared__ float gpart[16];
    __shared__ float p0L[32];

    const int b    = blockIdx.x;
    const int tid  = threadIdx.x;
    const int wave = tid >> 6;
    const int lane = tid & 63;
    const int c    = lane & 31;
    const int h    = lane >> 5;

    const float* frow = feats + (size_t)b * (Ln * Tn);
    const int*   trow = tags  + (size_t)b * Ln;

    // ---- per-row length (every wave, redundantly; no barrier needed) ----
    const bool boolLayout = (maskb[1] != 0);
    int cnt = 0;
    if (boolLayout) {
        const unsigned char* mrow = maskb + (size_t)b * Ln;
        uint2 v = ((const uint2*)mrow)[lane];            // 8 bytes/lane, each 0/1
        unsigned s8 = v.x + v.y;                         // per-byte sums <= 2
        cnt = (s8 & 0xff) + ((s8 >> 8) & 0xff) + ((s8 >> 16) & 0xff) + (s8 >> 24);
    } else {
        const int* mrow = (const int*)maskb + (size_t)b * Ln;
        uint4 a = ((const uint4*)mrow)[lane * 2];
        uint4 d = ((const uint4*)mrow)[lane * 2 + 1];
        cnt = (a.x!=0)+(a.y!=0)+(a.z!=0)+(a.w!=0)+(d.x!=0)+(d.y!=0)+(d.z!=0)+(d.w!=0);
    }
    cnt += __shfl_xor(cnt, 1);  cnt += __shfl_xor(cnt, 2);  cnt += __shfl_xor(cnt, 4);
    cnt += __shfl_xor(cnt, 8);  cnt += __shfl_xor(cnt, 16); cnt += __shfl_xor(cnt, 32);
    const int len = cnt;

    // ---- gold score partial (threads 0..511 <-> l = tid) ----
    float g = 0.f;
    if (wave < 8) {
        int l = tid;
        if (l < len) {
            int cur  = trow[l];
            int prev = l ? trow[l - 1] : START_S;
            g = frow[(size_t)l * Tn + cur] + trans[prev * Tn + cur];
            if (l == len - 1) g += trans[cur * Tn + STOP_S];
        }
        g += __shfl_xor(g, 1);  g += __shfl_xor(g, 2);  g += __shfl_xor(g, 4);
        g += __shfl_xor(g, 8);  g += __shfl_xor(g, 16); g += __shfl_xor(g, 32);
    }
    if (lane == 0) gpart[wave] = g;   // waves 8-15 write 0

    // ---- p0 (wave 8, lanes h==0): p0[j] = exp(feats[b][0][j] + trans[START][j]) ----
    if (wave == 8 && h == 0) p0L[c] = __expf(frow[c] + trans[START_S * Tn + c]);

    // ---- per-wave chunk product ----
    // WT: A[m][k] = E_l[m] * exp(trans[k][m]) / 64,  m = c, k = 8h+e (A1), 16+8h+e (A2)
    float WT1[8], WT2[8];
    #pragma unroll
    for (int e = 0; e < 8; ++e) {
        WT1[e] = __expf(trans[(8 * h + e) * Tn + c]) * 0.015625f;
        WT2[e] = __expf(trans[(16 + 8 * h + e) * Tn + c]) * 0.015625f;
    }

    const int start  = 1 + 32 * wave;
    int bound        = (33 + 32 * wave < len) ? (33 + 32 * wave) : len;
    const int nsteps = bound - start;   // may be <= 0 (identity chunk)

    // preload the chunk's feats column (lane c reads feats[b][l][c])
    float El[32];
    #pragma unroll
    for (int t = 0; t < 32; ++t) {
        int lc = start + t; lc = (lc > Ln - 1) ? (Ln - 1) : lc;
        El[t] = frow[(size_t)lc * Tn + c];
    }

    // Q = I  (f32 C-layout copy + bf16 B-frags)
    f32x16 Qf;
    #pragma unroll
    for (int r = 0; r < 16; ++r) {
        int row = (r & 3) + 8 * (r >> 2) + 4 * h;
        Qf[r] = (row == c) ? 1.f : 0.f;
    }
    FragU b1, b2;
    #pragma unroll
    for (int t = 0; t < 4; ++t) {
        int k0 = 8 * h + 2 * t;
        b1.u[t] = ((k0 == c) ? 0x3F80u : 0u) | (((k0 + 1 == c) ? 0x3F80u : 0u) << 16);
        int k2 = 16 + 8 * h + 2 * t;
        b2.u[t] = ((k2 == c) ? 0x3F80u : 0u) | (((k2 + 1 == c) ? 0x3F80u : 0u) << 16);
    }

    const f32x16 fz = {};
    #pragma unroll
    for (int t = 0; t < 32; ++t) {
        if (t < nsteps) {                       // wave-uniform predicate
            float E = __expf(El[t]);
            FragU a1, a2;
            a1.i[0] = cvt_pk(WT1[0]*E, WT1[1]*E);
            a1.i[1] = cvt_pk(WT1[2]*E, WT1[3]*E);
            a1.i[2] = cvt_pk(WT1[4]*E, WT1[5]*E);
            a1.i[3] = cvt_pk(WT1[6]*E, WT1[7]*E);
            a2.i[0] = cvt_pk(WT2[0]*E, WT2[1]*E);
            a2.i[1] = cvt_pk(WT2[2]*E, WT2[3]*E);
            a2.i[2] = cvt_pk(WT2[4]*E, WT2[5]*E);
            a2.i[3] = cvt_pk(WT2[6]*E, WT2[7]*E);

            f32x16 acc = __builtin_amdgcn_mfma_f32_32x32x16_bf16(a1.v, b1.v, fz, 0, 0, 0);
            acc = __builtin_amdgcn_mfma_f32_32x32x16_bf16(a2.v, b2.v, acc, 0, 0, 0);
            Qf = acc;

            // C -> B operand exchange (verified mapping from round 3)
            int q0 = cvt_pk(acc[0],  acc[1]),  q1 = cvt_pk(acc[2],  acc[3]);
            int q2 = cvt_pk(acc[4],  acc[5]),  q3 = cvt_pk(acc[6],  acc[7]);
            int q4 = cvt_pk(acc[8],  acc[9]),  q5 = cvt_pk(acc[10], acc[11]);
            int q6 = cvt_pk(acc[12], acc[13]), q7 = cvt_pk(acc[14], acc[15]);
            int s0 = __shfl_xor(q0, 32), s1 = __shfl_xor(q1, 32);
            int s2 = __shfl_xor(q2, 32), s3 = __shfl_xor(q3, 32);
            int s4 = __shfl_xor(q4, 32), s5 = __shfl_xor(q5, 32);
            int s6 = __shfl_xor(q6, 32), s7 = __shfl_xor(q7, 32);
            b1.i[0] = h ? s2 : q0;  b1.i[1] = h ? s3 : q1;
            b1.i[2] = h ? q2 : s0;  b1.i[3] = h ? q3 : s1;
            b2.i[0] = h ? s6 : q4;  b2.i[1] = h ? s7 : q5;
            b2.i[2] = h ? q6 : s4;  b2.i[3] = h ? q7 : s5;
        }
    }

    // normalize by entry [1][1] (row 1 = reg 1 of h=0, col 1 = lane 1) and store bf16
    {
        float norm = rdlane(Qf[1], 1);
        float inv  = 1.0f / norm;
        #pragma unroll
        for (int p = 0; p < 8; ++p) {
            int r = 2 * p;
            int row = (r & 3) + 8 * (r >> 2) + 4 * h;
            *(unsigned*)&QL[wave][c][row] = (unsigned)cvt_pk(Qf[r] * inv, Qf[r + 1] * inv);
        }
        if (lane == 0) logsL[wave] = __logf(norm);
    }
    __syncthreads();

    // ---- tree combine: R = Q_hi . Q_lo -> slot lo ----
    for (int d = 0; d < 4; ++d) {
        int nact = 8 >> d;
        if (wave < nact) {
            int span = 2 << d;
            int lo = wave * span;
            int hi = lo + (span >> 1);

            FragU A1, A2, B1f, B2f;
            #pragma unroll
            for (int t = 0; t < 4; ++t) {
                int kA = 8 * h + 2 * t;
                A1.u[t] = (unsigned)QL[hi][kA][c] | ((unsigned)QL[hi][kA + 1][c] << 16);
                int kB = 16 + 8 * h + 2 * t;
                A2.u[t] = (unsigned)QL[hi][kB][c] | ((unsigned)QL[hi][kB + 1][c] << 16);
                B1f.u[t] = *(const unsigned*)&QL[lo][c][8 * h + 2 * t];
                B2f.u[t] = *(const unsigned*)&QL[lo][c][16 + 8 * h + 2 * t];
            }
            f32x16 acc = __builtin_amdgcn_mfma_f32_32x32x16_bf16(A1.v, B1f.v, fz, 0, 0, 0);
            acc = __builtin_amdgcn_mfma_f32_32x32x16_bf16(A2.v, B2f.v, acc, 0, 0, 0);

            float norm = rdlane(acc[1], 1);
            float inv  = 1.0f / norm;
            #pragma unroll
            for (int p = 0; p < 8; ++p) {
                int r = 2 * p;
                int row = (r & 3) + 8 * (r >> 2) + 4 * h;
                *(unsigned*)&QL[lo][c][row] = (unsigned)cvt_pk(acc[r] * inv, acc[r + 1] * inv);
            }
            if (lane == 0) logsL[lo] += logsL[hi] + __logf(norm);
        }
        __syncthreads();
    }

    // ---- final: v = Root . p0; fwd = M + log(sum_j v_j * exp(trans[j][STOP])) ----
    if (wave == 0) {
        float part = 0.f;
        #pragma unroll
        for (int jj = 0; jj < 16; ++jj) {
            int jx = 16 * h + jj;
            part += bf2f(QL[0][jx][c]) * p0L[jx];   // Root[c][jx]
        }
        part += __shfl_xor(part, 32);               // v_c (both halves)
        float s = part * __expf(trans[c * Tn + STOP_S]);
        s += __shfl_xor(s, 1);  s += __shfl_xor(s, 2);  s += __shfl_xor(s, 4);
        s += __shfl_xor(s, 8);  s += __shfl_xor(s, 16);
        float fwd = (float)(len - 1) * LN64 + logsL[0] + __logf(s);
        if (lane == 0) {
            float gsum = 0.f;
            #pragma unroll
            for (int wv = 0; wv < 16; ++wv) gsum += gpart[wv];
            atomicAdd(out, fwd - gsum);
        }
    }
}

extern "C" void kernel_launch(void* const* d_in, const int* in_sizes, int n_in,
                              void* d_out, int out_size, void* d_ws, size_t ws_size,
                              hipStream_t stream) {
    const float* feats = (const float*)d_in[0];
    const unsigned char* maskb = (const unsigned char*)d_in[1];
    const int* tags = (const int*)d_in[2];
    const float* trans = (const float*)d_in[3];
    float* out = (float*)d_out;

    hipMemsetAsync(out, 0, sizeof(float), stream);
    crf_scan_kernel<<<Bn, 1024, 0, stream>>>(feats, maskb, tags, trans, out);
}